// Round 6
// baseline (225.427 us; speedup 1.0000x reference)
//
#include <hip/hip_runtime.h>
#include <hip/hip_bf16.h>

// Problem dims (fixed)
#define S_ 256
#define BSZ_ 64
#define IN_F_ 1024
#define OUT_F_ 512
#define USER_F_ 512

typedef short short8 __attribute__((ext_vector_type(8)));
typedef float f32x4 __attribute__((ext_vector_type(4)));

__device__ __forceinline__ ushort f2bf(float f) {
  unsigned u = __float_as_uint(f);
  unsigned r = (u + 0x7FFFu + ((u >> 16) & 1u)) >> 16;
  return (ushort)r;
}
__device__ __forceinline__ float bf2f(unsigned hi16) {
  return __uint_as_float(hi16 << 16);
}
// packed f32x2 -> bf16x2 (RNE, = f2bf bit-identical); lowers to v_cvt_pk_bf16_f32
__device__ __forceinline__ unsigned pkbf(float a, float b) {
  union { __hip_bfloat162 h; unsigned u; } x;
  x.h = __float22bfloat162_rn(float2{a, b});
  return x.u;
}
__device__ __forceinline__ float sigf(float x) {
  return 1.f / (1.f + __expf(-x));
}
__device__ __forceinline__ float tanh_safe(float x) {
  float ax = fabsf(x);
  float e = __expf(-2.f * ax);
  float r = (1.f - e) / (1.f + e);
  return copysignf(r, x);
}

// async global->LDS, 16B per lane; LDS dest = wave-uniform base + lane*16
__device__ __forceinline__ void gl_lds16(const ushort* g, ushort* l) {
  __builtin_amdgcn_global_load_lds(
      (const __attribute__((address_space(1))) void*)g,
      (__attribute__((address_space(3))) void*)l, 16, 0, 0);
}

// ---------------- prep: all weight converts + logit zero in ONE kernel -------
// ranges (in 256-thread units): Wd vec4 [0,131072) | Wu vec4 [131072,196608)
// | W transpose scalar [196608,458752) | zero rowlog/collog vec4 [458752,466944)
__global__ void prep(const float* __restrict__ Wd, const float* __restrict__ Wu,
                     const float* __restrict__ W, float* __restrict__ rowlog,
                     ushort* __restrict__ Wd_bf, ushort* __restrict__ Wu_bf,
                     ushort* __restrict__ Wt_bf) {
  int i = blockIdx.x * 256 + threadIdx.x;
  if (i < 131072) {
    float4 v = ((const float4*)Wd)[i];
    ushort4 o; o.x = f2bf(v.x); o.y = f2bf(v.y); o.z = f2bf(v.z); o.w = f2bf(v.w);
    ((ushort4*)Wd_bf)[i] = o;
  } else if (i < 196608) {
    int j = i - 131072;
    float4 v = ((const float4*)Wu)[j];
    ushort4 o; o.x = f2bf(v.x); o.y = f2bf(v.y); o.z = f2bf(v.z); o.w = f2bf(v.w);
    ((ushort4*)Wu_bf)[j] = o;
  } else if (i < 458752) {
    int j = i - 196608;             // out index e*512+d
    Wt_bf[j] = f2bf(W[(j & 511) * 512 + (j >> 9)]);
  } else {
    int j = i - 458752;
    ((float4*)rowlog)[j] = float4{0.f, 0.f, 0.f, 0.f};
  }
}

// ---------------- tile staging (R3/R5-proven) ----------------
// LDS row stride 64 shorts; 16B-chunk c of row r at phys slot c^(r&7).
template <int ROWS>
__device__ __forceinline__ void stage_tile(const ushort* __restrict__ g, int K,
                                           ushort* lds, int w, int lane) {
  const int rin = lane >> 3;  // 0..7
  const int c = lane & 7;     // 16B chunk slot within row
#pragma unroll
  for (int i = 0; i < ROWS / 32; ++i) {
    int r = w * (ROWS / 4) + i * 8 + rin;
    int gc = c ^ (r & 7);
    gl_lds16(g + (long)r * K + gc * 8, lds + w * (ROWS / 4) * 64 + i * 512);
  }
}

// A-tile (64x64) staged from FP32 source: load 16 floats/thread, HW packed
// cvt to bf16, 2x ds_write_b128 into the same swizzled layout. No registers
// held across barriers (R4 lesson).
__device__ __forceinline__ void stage_a_f32(const float* __restrict__ g, int K,
                                            ushort* As, int t) {
  const int row = t >> 2, seg = t & 3;
  const float4* p = (const float4*)(g + (long)row * K + seg * 16);
  float4 v0 = p[0], v1 = p[1], v2 = p[2], v3 = p[3];
  uint4 w0, w1;
  w0.x = pkbf(v0.x, v0.y); w0.y = pkbf(v0.z, v0.w);
  w0.z = pkbf(v1.x, v1.y); w0.w = pkbf(v1.z, v1.w);
  w1.x = pkbf(v2.x, v2.y); w1.y = pkbf(v2.z, v2.w);
  w1.z = pkbf(v3.x, v3.y); w1.w = pkbf(v3.z, v3.w);
  ushort* base = As + row * 64;
  *(uint4*)(base + ((seg * 2) ^ (row & 7)) * 8) = w0;
  *(uint4*)(base + ((seg * 2 + 1) ^ (row & 7)) * 8) = w1;
}

__device__ __forceinline__ short8 frag(const ushort* lds, int row, int kk, int q) {
  int pc = (kk * 4 + q) ^ (row & 7);
  return *(const short8*)(lds + row * 64 + pc * 8);
}

// BM=64 x BN=128, 4 waves as 2x2 (wave tile 32x64): acc[2][4]
__device__ __forceinline__ void compute_step(const ushort* As, const ushort* Bs,
                                             f32x4 acc[2][4], int wr, int wc,
                                             int mlane, int q) {
#pragma unroll
  for (int kk = 0; kk < 2; ++kk) {
    short8 af[2], bfr[4];
#pragma unroll
    for (int r = 0; r < 2; ++r) af[r] = frag(As, wr * 32 + r * 16 + mlane, kk, q);
#pragma unroll
    for (int c = 0; c < 4; ++c) bfr[c] = frag(Bs, wc * 64 + c * 16 + mlane, kk, q);
#pragma unroll
    for (int r = 0; r < 2; ++r)
#pragma unroll
      for (int c = 0; c < 4; ++c)
        acc[r][c] = __builtin_amdgcn_mfma_f32_16x16x32_bf16(af[r], bfr[c], acc[r][c], 0, 0, 0);
  }
}

// K-loop, A from bf16 (global_load_lds)
template <int NSTEP>
__device__ __forceinline__ void gemm_loop(const ushort* __restrict__ A,
                                          const ushort* __restrict__ B, int K,
                                          ushort* As, ushort* Bs, f32x4 acc[2][4],
                                          int w, int lane, int wr, int wc,
                                          int mlane, int q) {
#pragma unroll 1
  for (int k = 0; k < NSTEP; ++k) {
    stage_tile<64>(A + k * 64, K, As, w, lane);
    stage_tile<128>(B + k * 64, K, Bs, w, lane);
    __syncthreads();
    compute_step(As, Bs, acc, wr, wc, mlane, q);
    __syncthreads();
  }
}

// K-loop, A from FP32 (fused convert), B bf16 via global_load_lds
template <int NSTEP>
__device__ __forceinline__ void gemm_loop_f32a(const float* __restrict__ Af,
                                               const ushort* __restrict__ B, int K,
                                               ushort* As, ushort* Bs,
                                               f32x4 acc[2][4], int t, int w,
                                               int lane, int wr, int wc,
                                               int mlane, int q) {
#pragma unroll 1
  for (int k = 0; k < NSTEP; ++k) {
    stage_a_f32(Af + k * 64, K, As, t);
    stage_tile<128>(B + k * 64, K, Bs, w, lane);
    __syncthreads();
    compute_step(As, Bs, acc, wr, wc, mlane, q);
    __syncthreads();
  }
}

#define ACC_ZERO(a)                             \
  _Pragma("unroll") for (int r = 0; r < 2; ++r) \
  _Pragma("unroll") for (int c = 0; c < 4; ++c) { \
    a[r][c][0] = 0.f; a[r][c][1] = 0.f; a[r][c][2] = 0.f; a[r][c][3] = 0.f; }

// ---------------- fused convert + d/u GEMM + gating ----------------
// grid 1024 flat. XCD swizzle: i&7 = XCD; 4 x-blocks sharing an A-strip are
// consecutive j on one XCD -> A-strip fetched ~once per XCD L2.
__global__ __launch_bounds__(256, 4) void gemm_du(
    const float* __restrict__ Xd, const ushort* __restrict__ Wd,
    const float* __restrict__ bd,
    const float* __restrict__ Xu, const ushort* __restrict__ Wu,
    const float* __restrict__ bu,
    ushort* __restrict__ dg, ushort* __restrict__ ug) {
  __shared__ ushort sm[12288];  // As 64x64 (4096) + Bs 128x64 (8192) = 24KB
  ushort* As = sm; ushort* Bs = sm + 4096;
  const int i = blockIdx.x;
  const int k8 = i & 7, j = i >> 3;           // j in [0,128)
  const int by = k8 * 32 + (j >> 2), bx = j & 3;
  const int tid = threadIdx.x, lane = tid & 63, w = tid >> 6;
  const int wr = w >> 1, wc = w & 1, mlane = lane & 15, q = lane >> 4;
  const int m0 = by * 64, n0 = bx * 128;

  f32x4 accd[2][4]; ACC_ZERO(accd);
  gemm_loop_f32a<16>(Xd + (long)m0 * 1024, Wd + (long)n0 * 1024, 1024,
                     As, Bs, accd, tid, w, lane, wr, wc, mlane, q);
  f32x4 accu[2][4]; ACC_ZERO(accu);
  gemm_loop_f32a<8>(Xu + (long)m0 * 512, Wu + (long)n0 * 512, 512,
                    As, Bs, accu, tid, w, lane, wr, wc, mlane, q);

#pragma unroll
  for (int c = 0; c < 4; ++c) {
    const int gn = n0 + wc * 64 + c * 16 + mlane;
    const float bdv = bd[gn], buv = bu[gn];
#pragma unroll
    for (int r = 0; r < 2; ++r)
#pragma unroll
      for (int ii = 0; ii < 4; ++ii) {
        const int gm = m0 + wr * 32 + r * 16 + q * 4 + ii;
        const long idx = (long)gm * OUT_F_ + gn;
        float dp = accd[r][c][ii] + bdv;
        float up = accu[r][c][ii] + buv;
        float dgv = dp * sigf(up);
        float ugv = up * sigf(dgv);
        dg[idx] = f2bf(dgv);
        ug[idx] = f2bf(ugv);
      }
  }
}

// ---------------- t = dg * Wt^T ----------------
__global__ __launch_bounds__(256, 4) void gemm_t(
    const ushort* __restrict__ dgp, const ushort* __restrict__ Wt,
    ushort* __restrict__ tout) {
  __shared__ ushort sm[12288];
  ushort* As = sm; ushort* Bs = sm + 4096;
  const int i = blockIdx.x;
  const int k8 = i & 7, j = i >> 3;
  const int by = k8 * 32 + (j >> 2), bx = j & 3;
  const int tid = threadIdx.x, lane = tid & 63, w = tid >> 6;
  const int wr = w >> 1, wc = w & 1, mlane = lane & 15, q = lane >> 4;
  const int m0 = by * 64, n0 = bx * 128;

  f32x4 acc[2][4]; ACC_ZERO(acc);
  gemm_loop<8>(dgp + (long)m0 * 512, Wt + (long)n0 * 512, 512,
               As, Bs, acc, w, lane, wr, wc, mlane, q);

#pragma unroll
  for (int c = 0; c < 4; ++c) {
    const int gn = n0 + wc * 64 + c * 16 + mlane;
#pragma unroll
    for (int r = 0; r < 2; ++r)
#pragma unroll
      for (int ii = 0; ii < 4; ++ii) {
        const int gm = m0 + wr * 32 + r * 16 + q * 4 + ii;
        tout[(long)gm * OUT_F_ + gn] = f2bf(acc[r][c][ii]);
      }
  }
}

// ---------------- att tile + tanh + row/col sums (att never materialized) ----
__global__ __launch_bounds__(256, 4) void gemm_att(
    const ushort* __restrict__ t, const ushort* __restrict__ ug,
    float* __restrict__ rowlog, float* __restrict__ collog) {
  __shared__ ushort sm[12288];
  ushort* As = sm; ushort* Bs = sm + 4096;
  const int i = blockIdx.x;
  const int k8 = i & 7, j = i >> 3;           // j in [0,64)
  const int b = k8 * 8 + (j >> 3);            // 8 batches per XCD
  const int l = j & 7, by = l >> 1, bx = l & 1;
  const int tid = threadIdx.x, lane = tid & 63, w = tid >> 6;
  const int wr = w >> 1, wc = w & 1, mlane = lane & 15, q = lane >> 4;
  const ushort* A = t + (long)b * (S_ * OUT_F_) + (long)by * 64 * 512;
  const ushort* B = ug + (long)b * (S_ * OUT_F_) + (long)bx * 128 * 512;

  f32x4 acc[2][4]; ACC_ZERO(acc);
  gemm_loop<8>(A, B, 512, As, Bs, acc, w, lane, wr, wc, mlane, q);

  float rs[2][4], cs[4];
#pragma unroll
  for (int r = 0; r < 2; ++r)
#pragma unroll
    for (int ii = 0; ii < 4; ++ii) rs[r][ii] = 0.f;
#pragma unroll
  for (int c = 0; c < 4; ++c) cs[c] = 0.f;
#pragma unroll
  for (int r = 0; r < 2; ++r)
#pragma unroll
    for (int c = 0; c < 4; ++c)
#pragma unroll
      for (int ii = 0; ii < 4; ++ii) {
        float v = tanh_safe(acc[r][c][ii]);
        rs[r][ii] += v;
        cs[c] += v;
      }
#pragma unroll
  for (int m = 1; m < 16; m <<= 1)
#pragma unroll
    for (int r = 0; r < 2; ++r)
#pragma unroll
      for (int ii = 0; ii < 4; ++ii) rs[r][ii] += __shfl_xor(rs[r][ii], m, 64);
#pragma unroll
  for (int m = 16; m < 64; m <<= 1)
#pragma unroll
    for (int c = 0; c < 4; ++c) cs[c] += __shfl_xor(cs[c], m, 64);

  float* rsum = (float*)sm;          // [64]
  float* csum = ((float*)sm) + 64;   // [128]
  if (tid < 64) rsum[tid] = 0.f;
  else if (tid < 192) csum[tid - 64] = 0.f;
  __syncthreads();
  if (mlane == 0) {
#pragma unroll
    for (int r = 0; r < 2; ++r)
#pragma unroll
      for (int ii = 0; ii < 4; ++ii)
        atomicAdd(&rsum[wr * 32 + r * 16 + q * 4 + ii], rs[r][ii]);
  }
  if (q == 0) {
#pragma unroll
    for (int c = 0; c < 4; ++c) atomicAdd(&csum[wc * 64 + c * 16 + mlane], cs[c]);
  }
  __syncthreads();
  if (tid < 64)
    atomicAdd(&rowlog[b * S_ + by * 64 + tid], rsum[tid]);
  else if (tid < 192)
    atomicAdd(&collog[b * S_ + bx * 128 + (tid - 64)], csum[tid - 64]);
}

// ---------------- finalize ----------------
__device__ __forceinline__ float block_max(float v, float* buf, int tid) {
  buf[tid] = v; __syncthreads();
  for (int s = 128; s > 0; s >>= 1) {
    if (tid < s) buf[tid] = fmaxf(buf[tid], buf[tid + s]);
    __syncthreads();
  }
  float r = buf[0]; __syncthreads();
  return r;
}
__device__ __forceinline__ float block_sum(float v, float* buf, int tid) {
  buf[tid] = v; __syncthreads();
  for (int s = 128; s > 0; s >>= 1) {
    if (tid < s) buf[tid] = buf[tid] + buf[tid + s];
    __syncthreads();
  }
  float r = buf[0]; __syncthreads();
  return r;
}

__global__ __launch_bounds__(256) void finalize(
    const float* __restrict__ rowlog, const float* __restrict__ collog,
    const ushort* __restrict__ dg, const ushort* __restrict__ ug,
    float* __restrict__ out) {
  __shared__ float sd[S_], su[S_], buf[S_];
  const int b = blockIdx.x, tid = threadIdx.x;

  const float rowmean = rowlog[b * S_ + tid] * (1.f / (float)S_);
  const float colmean = collog[b * S_ + tid] * (1.f / (float)S_);

  float md = block_max(rowmean, buf, tid);
  float ed = __expf(rowmean - md);
  float sds = block_sum(ed, buf, tid);
  sd[tid] = ed / sds;
  float mu = block_max(colmean, buf, tid);
  float eu = __expf(colmean - mu);
  float sus = block_sum(eu, buf, tid);
  su[tid] = eu / sus;
  __syncthreads();

  const ushort* dgb = dg + (long)b * (S_ * OUT_F_);
  const ushort* ugb = ug + (long)b * (S_ * OUT_F_);
  float ad0 = 0.f, ad1 = 0.f, au0 = 0.f, au1 = 0.f;
  const int o = 2 * tid;
  for (int s = 0; s < S_; ++s) {
    const float wd = sd[s], wu = su[s];
    unsigned dv = *(const unsigned*)(dgb + s * OUT_F_ + o);
    unsigned uv = *(const unsigned*)(ugb + s * OUT_F_ + o);
    ad0 += wd * bf2f(dv & 0xffffu); ad1 += wd * bf2f(dv >> 16);
    au0 += wu * bf2f(uv & 0xffffu); au1 += wu * bf2f(uv >> 16);
  }
  out[b * OUT_F_ + o] = ad0;
  out[b * OUT_F_ + o + 1] = ad1;
  out[BSZ_ * OUT_F_ + b * OUT_F_ + o] = au0;
  out[BSZ_ * OUT_F_ + b * OUT_F_ + o + 1] = au1;
}

extern "C" void kernel_launch(void* const* d_in, const int* in_sizes, int n_in,
                              void* d_out, int out_size, void* d_ws, size_t ws_size,
                              hipStream_t stream) {
  (void)in_sizes; (void)n_in; (void)out_size; (void)ws_size;
  const float* Xd = (const float*)d_in[0];
  const float* Xu = (const float*)d_in[1];
  const float* Wd = (const float*)d_in[2];
  const float* bd = (const float*)d_in[3];
  const float* Wu = (const float*)d_in[4];
  const float* bu = (const float*)d_in[5];
  const float* W  = (const float*)d_in[6];
  float* out = (float*)d_out;
  char* ws = (char*)d_ws;

  ushort* Wd_bf  = (ushort*)(ws + 0L);          //  1,048,576
  ushort* Wu_bf  = (ushort*)(ws + 1048576L);    //    524,288
  ushort* Wt_bf  = (ushort*)(ws + 1572864L);    //    524,288
  ushort* dg     = (ushort*)(ws + 2097152L);    // 16,777,216
  ushort* ug     = (ushort*)(ws + 18874368L);   // 16,777,216
  ushort* t_bf   = (ushort*)(ws + 35651584L);   // 16,777,216
  float*  rowlog = (float*)(ws + 52428800L);    //     65,536
  float*  collog = (float*)(ws + 52494336L);    //     65,536 (contiguous w/ rowlog)

  prep<<<1824, 256, 0, stream>>>(Wd, Wu, W, rowlog, Wd_bf, Wu_bf, Wt_bf);

  dim3 blk(256);
  gemm_du<<<1024, blk, 0, stream>>>(Xd, Wd_bf, bd, Xu, Wu_bf, bu, dg, ug);
  gemm_t<<<1024, blk, 0, stream>>>(dg, Wt_bf, t_bf);
  gemm_att<<<512, blk, 0, stream>>>(t_bf, ug, rowlog, collog);
  finalize<<<64, 256, 0, stream>>>(rowlog, collog, dg, ug, out);
}

// Round 7
// 222.166 us; speedup vs baseline: 1.0147x; 1.0147x over previous
//
#include <hip/hip_runtime.h>
#include <hip/hip_bf16.h>

// Problem dims (fixed)
#define S_ 256
#define BSZ_ 64
#define IN_F_ 1024
#define OUT_F_ 512
#define USER_F_ 512

typedef short short8 __attribute__((ext_vector_type(8)));
typedef float f32x4 __attribute__((ext_vector_type(4)));

__device__ __forceinline__ ushort f2bf(float f) {
  unsigned u = __float_as_uint(f);
  unsigned r = (u + 0x7FFFu + ((u >> 16) & 1u)) >> 16;
  return (ushort)r;
}
__device__ __forceinline__ float bf2f(unsigned hi16) {
  return __uint_as_float(hi16 << 16);
}
__device__ __forceinline__ float sigf(float x) {
  return 1.f / (1.f + __expf(-x));
}
__device__ __forceinline__ float tanh_safe(float x) {
  float ax = fabsf(x);
  float e = __expf(-2.f * ax);
  float r = (1.f - e) / (1.f + e);
  return copysignf(r, x);
}

// async global->LDS, 16B per lane; LDS dest = wave-uniform base + lane*16
__device__ __forceinline__ void gl_lds16(const ushort* g, ushort* l) {
  __builtin_amdgcn_global_load_lds(
      (const __attribute__((address_space(1))) void*)g,
      (__attribute__((address_space(3))) void*)l, 16, 0, 0);
}

// ---------------- prep: ALL converts + logit zero in ONE kernel -------------
// ranges (256-thread units, cumulative):
//   Xd vec4 [0, 4194304) | Xu vec4 [4194304, 6291456) | Wd vec4 [.., 6422528)
//   Wu vec4 [.., 6488064) | W-transpose scalar [.., 6750208) | zero [.., 6758400)
__global__ void prep(const float* __restrict__ Xd, const float* __restrict__ Xu,
                     const float* __restrict__ Wd, const float* __restrict__ Wu,
                     const float* __restrict__ W,
                     ushort* __restrict__ Xd_bf, ushort* __restrict__ Xu_bf,
                     ushort* __restrict__ Wd_bf, ushort* __restrict__ Wu_bf,
                     ushort* __restrict__ Wt_bf, float* __restrict__ rowlog) {
  int i = blockIdx.x * 256 + threadIdx.x;
  if (i < 4194304) {
    float4 v = ((const float4*)Xd)[i];
    ushort4 o; o.x = f2bf(v.x); o.y = f2bf(v.y); o.z = f2bf(v.z); o.w = f2bf(v.w);
    ((ushort4*)Xd_bf)[i] = o;
  } else if (i < 6291456) {
    int j = i - 4194304;
    float4 v = ((const float4*)Xu)[j];
    ushort4 o; o.x = f2bf(v.x); o.y = f2bf(v.y); o.z = f2bf(v.z); o.w = f2bf(v.w);
    ((ushort4*)Xu_bf)[j] = o;
  } else if (i < 6422528) {
    int j = i - 6291456;
    float4 v = ((const float4*)Wd)[j];
    ushort4 o; o.x = f2bf(v.x); o.y = f2bf(v.y); o.z = f2bf(v.z); o.w = f2bf(v.w);
    ((ushort4*)Wd_bf)[j] = o;
  } else if (i < 6488064) {
    int j = i - 6422528;
    float4 v = ((const float4*)Wu)[j];
    ushort4 o; o.x = f2bf(v.x); o.y = f2bf(v.y); o.z = f2bf(v.z); o.w = f2bf(v.w);
    ((ushort4*)Wu_bf)[j] = o;
  } else if (i < 6750208) {
    int j = i - 6488064;  // out index e*512+d -> W[d*512+e]
    Wt_bf[j] = f2bf(W[(j & 511) * 512 + (j >> 9)]);
  } else {
    int j = i - 6750208;  // zero rowlog+collog (contiguous 32768 floats)
    ((float4*)rowlog)[j] = float4{0.f, 0.f, 0.f, 0.f};
  }
}

// ---------------- tile staging (R3/R5-proven) ----------------
// LDS row stride 64 shorts; 16B-chunk c of row r at phys slot c^(r&7).
template <int ROWS>
__device__ __forceinline__ void stage_tile(const ushort* __restrict__ g, int K,
                                           ushort* lds, int w, int lane) {
  const int rin = lane >> 3;  // 0..7
  const int c = lane & 7;     // 16B chunk slot within row
#pragma unroll
  for (int i = 0; i < ROWS / 32; ++i) {
    int r = w * (ROWS / 4) + i * 8 + rin;
    int gc = c ^ (r & 7);
    gl_lds16(g + (long)r * K + gc * 8, lds + w * (ROWS / 4) * 64 + i * 512);
  }
}
// ROWS=32 variant: one chunk per wave (wave w stages rows w*8..w*8+8)
__device__ __forceinline__ void stage_tile32(const ushort* __restrict__ g, int K,
                                             ushort* lds, int w, int lane) {
  const int rin = lane >> 3, c = lane & 7;
  int r = w * 8 + rin;
  int gc = c ^ (r & 7);
  gl_lds16(g + (long)r * K + gc * 8, lds + w * 512);
}

__device__ __forceinline__ short8 frag(const ushort* lds, int row, int kk, int q) {
  int pc = (kk * 4 + q) ^ (row & 7);
  return *(const short8*)(lds + row * 64 + pc * 8);
}
// t_lds variant: row stride 512 shorts, K-window k (64 cols each)
__device__ __forceinline__ short8 frag512(const ushort* lds, int row, int k,
                                          int kk, int q) {
  int pc = (kk * 4 + q) ^ (row & 7);
  return *(const short8*)(lds + row * 512 + k * 64 + pc * 8);
}

// BM=64 x BN=128, 4 waves as 2x2 (wave tile 32x64): acc[2][4]
__device__ __forceinline__ void compute_step(const ushort* As, const ushort* Bs,
                                             f32x4 acc[2][4], int wr, int wc,
                                             int mlane, int q) {
#pragma unroll
  for (int kk = 0; kk < 2; ++kk) {
    short8 af[2], bfr[4];
#pragma unroll
    for (int r = 0; r < 2; ++r) af[r] = frag(As, wr * 32 + r * 16 + mlane, kk, q);
#pragma unroll
    for (int c = 0; c < 4; ++c) bfr[c] = frag(Bs, wc * 64 + c * 16 + mlane, kk, q);
#pragma unroll
    for (int r = 0; r < 2; ++r)
#pragma unroll
      for (int c = 0; c < 4; ++c)
        acc[r][c] = __builtin_amdgcn_mfma_f32_16x16x32_bf16(af[r], bfr[c], acc[r][c], 0, 0, 0);
  }
}

// K-loop (R5-proven): stage -> sync -> compute -> sync
template <int NSTEP>
__device__ __forceinline__ void gemm_loop(const ushort* __restrict__ A,
                                          const ushort* __restrict__ B, int K,
                                          ushort* As, ushort* Bs, f32x4 acc[2][4],
                                          int w, int lane, int wr, int wc,
                                          int mlane, int q) {
#pragma unroll 1
  for (int k = 0; k < NSTEP; ++k) {
    stage_tile<64>(A + k * 64, K, As, w, lane);
    stage_tile<128>(B + k * 64, K, Bs, w, lane);
    __syncthreads();
    compute_step(As, Bs, acc, wr, wc, mlane, q);
    __syncthreads();
  }
}

#define ACC_ZERO(a)                             \
  _Pragma("unroll") for (int r = 0; r < 2; ++r) \
  _Pragma("unroll") for (int c = 0; c < 4; ++c) { \
    a[r][c][0] = 0.f; a[r][c][1] = 0.f; a[r][c][2] = 0.f; a[r][c][3] = 0.f; }

// ---------------- fused d/u GEMM + gating (R5-proven form) ----------------
__global__ __launch_bounds__(256, 4) void gemm_du(
    const ushort* __restrict__ Xd, const ushort* __restrict__ Wd,
    const float* __restrict__ bd,
    const ushort* __restrict__ Xu, const ushort* __restrict__ Wu,
    const float* __restrict__ bu,
    ushort* __restrict__ dg, ushort* __restrict__ ug) {
  __shared__ ushort sm[12288];  // As 64x64 (4096) + Bs 128x64 (8192) = 24KB
  ushort* As = sm; ushort* Bs = sm + 4096;
  const int i = blockIdx.x;
  const int k8 = i & 7, j = i >> 3;           // j in [0,128)
  const int by = k8 * 32 + (j >> 2), bx = j & 3;
  const int tid = threadIdx.x, lane = tid & 63, w = tid >> 6;
  const int wr = w >> 1, wc = w & 1, mlane = lane & 15, q = lane >> 4;
  const int m0 = by * 64, n0 = bx * 128;

  f32x4 accd[2][4]; ACC_ZERO(accd);
  gemm_loop<16>(Xd + (long)m0 * 1024, Wd + (long)n0 * 1024, 1024,
                As, Bs, accd, w, lane, wr, wc, mlane, q);
  f32x4 accu[2][4]; ACC_ZERO(accu);
  gemm_loop<8>(Xu + (long)m0 * 512, Wu + (long)n0 * 512, 512,
               As, Bs, accu, w, lane, wr, wc, mlane, q);

#pragma unroll
  for (int c = 0; c < 4; ++c) {
    const int gn = n0 + wc * 64 + c * 16 + mlane;
    const float bdv = bd[gn], buv = bu[gn];
#pragma unroll
    for (int r = 0; r < 2; ++r)
#pragma unroll
      for (int ii = 0; ii < 4; ++ii) {
        const int gm = m0 + wr * 32 + r * 16 + q * 4 + ii;
        const long idx = (long)gm * OUT_F_ + gn;
        float dp = accd[r][c][ii] + bdv;
        float up = accu[r][c][ii] + buv;
        float dgv = dp * sigf(up);
        float ugv = up * sigf(dgv);
        dg[idx] = f2bf(dgv);
        ug[idx] = f2bf(ugv);
      }
  }
}

// ---------------- fused t-GEMM + att-GEMM + tanh + reductions ----------------
// Block = (batch b, 32-row s-strip by). Phase 1: t[32][512] = dg_strip . Wt^T
// computed in 4 col-chunks, written bf16 into LDS (XOR-swizzled, frag-readable).
// Phase 2: att[32][256] = t . ug^T straight from LDS (no A staging), tanh,
// row sums -> rowlog (direct store), col sums -> collog (atomic).
// LDS: t 32KB + stage 32KB = 64KB -> 2 blocks/CU.
__global__ __launch_bounds__(256, 2) void gemm_tatt(
    const ushort* __restrict__ dg, const ushort* __restrict__ Wt,
    const ushort* __restrict__ ug, float* __restrict__ rowlog,
    float* __restrict__ collog) {
  __shared__ ushort sm[32768];  // 64KB
  ushort* t_lds = sm;           // [32][512] shorts = 32KB
  ushort* AsT = sm + 16384;     // t-phase A stage: 32x64 = 4KB
  ushort* BsT = sm + 18432;     // t-phase B stage: 128x64 = 16KB
  ushort* BsU = sm + 16384;     // att-phase B stage: 256x64 = 32KB (aliases)
  const int i = blockIdx.x;
  const int xcd = i & 7, j = i >> 3;   // j in [0,64)
  const int b = xcd * 8 + (j >> 3);    // batch; 8 blocks of b share one XCD L2
  const int by = j & 7;                // 32-row s-strip
  const int tid = threadIdx.x, lane = tid & 63, w = tid >> 6;
  const int mlane = lane & 15, q = lane >> 4;
  const ushort* dgs = dg + (long)b * (S_ * OUT_F_) + (long)by * 32 * 512;
  const ushort* ugb = ug + (long)b * (S_ * OUT_F_);

  // ---- phase 1: t strip. waves 1x4 over cols (wave w: cols w*32 of 128-chunk)
#pragma unroll 1
  for (int nc = 0; nc < 4; ++nc) {
    f32x4 acc[2][2];
#pragma unroll
    for (int r = 0; r < 2; ++r)
#pragma unroll
      for (int c = 0; c < 2; ++c) {
        acc[r][c][0] = 0.f; acc[r][c][1] = 0.f; acc[r][c][2] = 0.f; acc[r][c][3] = 0.f;
      }
    const ushort* Bw = Wt + (long)(nc * 128) * 512;
#pragma unroll 1
    for (int k = 0; k < 8; ++k) {
      stage_tile32(dgs + k * 64, 512, AsT, w, lane);
      stage_tile<128>(Bw + k * 64, 512, BsT, w, lane);
      __syncthreads();
#pragma unroll
      for (int kk = 0; kk < 2; ++kk) {
        short8 af[2], bfr[2];
#pragma unroll
        for (int r = 0; r < 2; ++r) af[r] = frag(AsT, r * 16 + mlane, kk, q);
#pragma unroll
        for (int c = 0; c < 2; ++c)
          bfr[c] = frag(BsT, w * 32 + c * 16 + mlane, kk, q);
#pragma unroll
        for (int r = 0; r < 2; ++r)
#pragma unroll
          for (int c = 0; c < 2; ++c)
            acc[r][c] = __builtin_amdgcn_mfma_f32_16x16x32_bf16(af[r], bfr[c], acc[r][c], 0, 0, 0);
      }
      __syncthreads();
    }
    // write chunk to t_lds (bf16), swizzled so frag512 reads it directly
#pragma unroll
    for (int r = 0; r < 2; ++r)
#pragma unroll
      for (int c = 0; c < 2; ++c)
#pragma unroll
        for (int ii = 0; ii < 4; ++ii) {
          int rr = r * 16 + q * 4 + ii;
          int col = nc * 128 + w * 32 + c * 16 + mlane;
          int cc = col >> 3;
          int ph = (cc & ~7) | ((cc & 7) ^ (rr & 7));
          t_lds[rr * 512 + ph * 8 + (col & 7)] = f2bf(acc[r][c][ii]);
        }
    // no extra sync: t_lds region disjoint from stages; lgkm drained at next barrier
  }

  // ---- phase 2: att = t . ug^T. waves 1x4 over cols (wave w: r-cols w*64)
  f32x4 acc[2][4]; ACC_ZERO(acc);
#pragma unroll 1
  for (int k = 0; k < 8; ++k) {
    stage_tile<256>(ugb + k * 64, 512, BsU, w, lane);
    __syncthreads();  // also guarantees all waves' t_lds writes visible (k==0)
#pragma unroll
    for (int kk = 0; kk < 2; ++kk) {
      short8 af[2], bfr[4];
#pragma unroll
      for (int r = 0; r < 2; ++r) af[r] = frag512(t_lds, r * 16 + mlane, k, kk, q);
#pragma unroll
      for (int c = 0; c < 4; ++c)
        bfr[c] = frag(BsU, w * 64 + c * 16 + mlane, kk, q);
#pragma unroll
      for (int r = 0; r < 2; ++r)
#pragma unroll
        for (int c = 0; c < 4; ++c)
          acc[r][c] = __builtin_amdgcn_mfma_f32_16x16x32_bf16(af[r], bfr[c], acc[r][c], 0, 0, 0);
    }
    __syncthreads();
  }

  // tanh + reductions. rows (s) = r*16+q*4+ii (all waves same 32 rows);
  // cols (r-index) = w*64 + c*16 + mlane (waves own disjoint col ranges).
  float rs[8], cs[4];
#pragma unroll
  for (int x = 0; x < 8; ++x) rs[x] = 0.f;
#pragma unroll
  for (int c = 0; c < 4; ++c) cs[c] = 0.f;
#pragma unroll
  for (int r = 0; r < 2; ++r)
#pragma unroll
    for (int c = 0; c < 4; ++c)
#pragma unroll
      for (int ii = 0; ii < 4; ++ii) {
        float v = tanh_safe(acc[r][c][ii]);
        rs[r * 4 + ii] += v;
        cs[c] += v;
      }
#pragma unroll
  for (int m = 1; m < 16; m <<= 1)
#pragma unroll
    for (int x = 0; x < 8; ++x) rs[x] += __shfl_xor(rs[x], m, 64);
#pragma unroll
  for (int m = 16; m < 64; m <<= 1)
#pragma unroll
    for (int c = 0; c < 4; ++c) cs[c] += __shfl_xor(cs[c], m, 64);

  float* rsum = (float*)BsU;  // stage dead after last sync
  if (tid < 32) rsum[tid] = 0.f;
  __syncthreads();
  if (mlane == 0) {
#pragma unroll
    for (int x = 0; x < 8; ++x)
      atomicAdd(&rsum[(x >> 2) * 16 + q * 4 + (x & 3)], rs[x]);
  }
  if (q == 0) {
#pragma unroll
    for (int c = 0; c < 4; ++c)
      atomicAdd(&collog[b * S_ + w * 64 + c * 16 + mlane], cs[c]);
  }
  __syncthreads();
  if (tid < 32) rowlog[b * S_ + by * 32 + tid] = rsum[tid];
}

// ---------------- finalize: softmax + weighted sums, 4x parallel -------------
__device__ __forceinline__ float block_max(float v, float* buf, int tid) {
  buf[tid] = v; __syncthreads();
  for (int s = 128; s > 0; s >>= 1) {
    if (tid < s) buf[tid] = fmaxf(buf[tid], buf[tid + s]);
    __syncthreads();
  }
  float r = buf[0]; __syncthreads();
  return r;
}
__device__ __forceinline__ float block_sum(float v, float* buf, int tid) {
  buf[tid] = v; __syncthreads();
  for (int s = 128; s > 0; s >>= 1) {
    if (tid < s) buf[tid] = buf[tid] + buf[tid + s];
    __syncthreads();
  }
  float r = buf[0]; __syncthreads();
  return r;
}

__global__ __launch_bounds__(256) void finalize(
    const float* __restrict__ rowlog, const float* __restrict__ collog,
    const ushort* __restrict__ dg, const ushort* __restrict__ ug,
    float* __restrict__ out) {
  __shared__ float sd[S_], su[S_], buf[S_];
  const int b = blockIdx.x >> 2, oc = blockIdx.x & 3;
  const int tid = threadIdx.x;

  const float rowmean = rowlog[b * S_ + tid] * (1.f / (float)S_);
  const float colmean = collog[b * S_ + tid] * (1.f / (float)S_);

  float md = block_max(rowmean, buf, tid);
  float ed = __expf(rowmean - md);
  float sds = block_sum(ed, buf, tid);
  sd[tid] = ed / sds;
  float mu = block_max(colmean, buf, tid);
  float eu = __expf(colmean - mu);
  float sus = block_sum(eu, buf, tid);
  su[tid] = eu / sus;
  __syncthreads();

  const int o = oc * 128 + (tid & 127);
  const ushort* src = (tid < 128) ? dg : ug;
  const float* sw = (tid < 128) ? sd : su;
  const ushort* p = src + (long)b * (S_ * OUT_F_) + o;
  float a = 0.f;
  for (int s = 0; s < S_; ++s) a += sw[s] * bf2f((unsigned)p[s * OUT_F_]);
  out[((tid < 128) ? 0 : BSZ_ * OUT_F_) + b * OUT_F_ + o] = a;
}

extern "C" void kernel_launch(void* const* d_in, const int* in_sizes, int n_in,
                              void* d_out, int out_size, void* d_ws, size_t ws_size,
                              hipStream_t stream) {
  (void)in_sizes; (void)n_in; (void)out_size; (void)ws_size;
  const float* Xd = (const float*)d_in[0];
  const float* Xu = (const float*)d_in[1];
  const float* Wd = (const float*)d_in[2];
  const float* bd = (const float*)d_in[3];
  const float* Wu = (const float*)d_in[4];
  const float* bu = (const float*)d_in[5];
  const float* W  = (const float*)d_in[6];
  float* out = (float*)d_out;
  char* ws = (char*)d_ws;

  ushort* Xd_bf  = (ushort*)(ws + 0L);          // 33,554,432
  ushort* Xu_bf  = (ushort*)(ws + 33554432L);   // 16,777,216
  ushort* Wd_bf  = (ushort*)(ws + 50331648L);   //  1,048,576
  ushort* Wu_bf  = (ushort*)(ws + 51380224L);   //    524,288
  ushort* Wt_bf  = (ushort*)(ws + 51904512L);   //    524,288
  ushort* dg     = (ushort*)(ws + 52428800L);   // 16,777,216
  ushort* ug     = (ushort*)(ws + 69206016L);   // 16,777,216
  float*  rowlog = (float*)(ws + 85983232L);    //     65,536
  float*  collog = (float*)(ws + 86048768L);    //     65,536 (contiguous)

  prep<<<26400, 256, 0, stream>>>(Xd, Xu, Wd, Wu, W, Xd_bf, Xu_bf,
                                  Wd_bf, Wu_bf, Wt_bf, rowlog);

  dim3 blk(256);
  gemm_du<<<1024, blk, 0, stream>>>(Xd_bf, Wd_bf, bd, Xu_bf, Wu_bf, bu, dg, ug);
  gemm_tatt<<<512, blk, 0, stream>>>(dg, Wt_bf, ug, rowlog, collog);
  finalize<<<256, 256, 0, stream>>>(rowlog, collog, dg, ug, out);
}